// Round 6
// baseline (19.535 us; speedup 1.0000x reference)
//
#include <hip/hip_runtime.h>

// Geometry:
//   x : (1,24,56,56) f32  -> c*3136 + h*56 + w
//   w1: (96,3,21)    f32  -> i*63 + j*21 + k
//   w2: (12,7,21)    f32  -> c*147 + jj*21 + k
//   y : (1,96,56,56) f32  -> i*3136 + h*56 + w
//
// t3r[c,h,w] = x[c,h,(w-1)%56] + x[c+12,h,(w-1)%56]          (roll +1 width)
// t5[h,w,k]  = sum_{c<12,jj<7} t3r[c,h,w+jj-3] * w2[c,jj,k]   (zero width-pad)
// y[i,h,w]   = sum_{j<3,k<21}  t5[h+j-1,w,k]  * w1[i,j,k]     (zero height-pad)
//
// R5: one dispatch, 224 blocks (56 h x 4 i-chunks of 24) x 256 thr
// -> 1 wave/SIMD on 224 CUs, zero issue contention. Stage-1 t5 recompute
// per i-chunk is cheap in register/scalar form (1512 FMA + 252 ds_read per
// wave). k-groups of 6 at k0 = wid*5 overlap at k=5,10,15: both waves write
// bit-identical values (same FMA order, same inputs) -> benign.

#define NH 56
#define NW 56
#define NC 12
#define NK 21
#define NI 96
#define ICHUNK 24

__global__ __launch_bounds__(256)
void fused_kernel(const float* __restrict__ x,
                  const float* __restrict__ w1,
                  const float* __restrict__ w2,
                  float* __restrict__ y) {
    __shared__ float s_t3[3][NC][NW + 6];   // 2232 f32, 8.9 KB (p <-> ww = p-3)
    __shared__ float s_t5[3][NW * NK];      // 3528 f32, 14.1 KB

    const int h    = blockIdx.x;
    const int i0   = blockIdx.y * ICHUNK;
    const int tid  = threadIdx.x;
    const int wid  = tid >> 6;
    const int lane = tid & 63;

    // --- stage t3 rows h-1..h+1 (pair-sum + width-roll, zero-pad h and w) ---
    for (int e = tid; e < 3 * NC * (NW + 6); e += 256) {
        const int r = e / (NC * (NW + 6));
        const int c = (e / (NW + 6)) % NC;
        const int p = e % (NW + 6);
        const int hh = h - 1 + r;
        const int ww = p - 3;
        float v = 0.0f;
        if (hh >= 0 && hh < NH && ww >= 0 && ww < NW) {
            const int wsrc = (ww + NW - 1) % NW;   // roll(+1): out[w] = in[w-1]
            const int base = hh * NW + wsrc;
            v = x[c * 3136 + base] + x[(c + 12) * 3136 + base];
        }
        s_t3[r][c][p] = v;
    }
    __syncthreads();

    // --- stage 1: wave wid computes k-group [k0, k0+6) for all 3 rows ---
    const int k0 = __builtin_amdgcn_readfirstlane(wid * 5);   // 0,5,10,15
    if (lane < NW) {
        const int w = lane;
        #pragma unroll
        for (int r = 0; r < 3; ++r) {
            float acc[6] = {0.f, 0.f, 0.f, 0.f, 0.f, 0.f};
            for (int c = 0; c < NC; ++c) {
                float win[7];
                #pragma unroll
                for (int jj = 0; jj < 7; ++jj) win[jj] = s_t3[r][c][w + jj];
                const float* __restrict__ wp = w2 + c * 147 + k0;  // SGPR base
                #pragma unroll
                for (int kk = 0; kk < 6; ++kk) {
                    float a = acc[kk];
                    #pragma unroll
                    for (int jj = 0; jj < 7; ++jj) a += win[jj] * wp[jj * NK + kk];
                    acc[kk] = a;
                }
            }
            #pragma unroll
            for (int kk = 0; kk < 6; ++kk) s_t5[r][w * NK + k0 + kk] = acc[kk];
        }
    }
    __syncthreads();

    // --- stage 2: wave wid -> 6 output channels of this block's 24 ---
    if (lane < NW) {
        const int w = lane;
        float v[3][NK];
        #pragma unroll
        for (int j = 0; j < 3; ++j) {
            #pragma unroll
            for (int k = 0; k < NK; ++k) v[j][k] = s_t5[j][w * NK + k];
        }
        const int ibase = __builtin_amdgcn_readfirstlane(i0 + wid * 6);
        #pragma unroll
        for (int il = 0; il < 6; ++il) {
            const int i = ibase + il;
            const float* __restrict__ wp = w1 + i * 63;            // SGPR base
            float acc = 0.0f;
            #pragma unroll
            for (int j = 0; j < 3; ++j) {
                #pragma unroll
                for (int k = 0; k < NK; ++k) acc += v[j][k] * wp[j * NK + k];
            }
            y[i * 3136 + h * NW + w] = acc;
        }
    }
}

extern "C" void kernel_launch(void* const* d_in, const int* in_sizes, int n_in,
                              void* d_out, int out_size, void* d_ws, size_t ws_size,
                              hipStream_t stream) {
    const float* x  = (const float*)d_in[0];
    const float* w1 = (const float*)d_in[1];
    const float* w2 = (const float*)d_in[2];
    float* y = (float*)d_out;
    fused_kernel<<<dim3(NH, NI / ICHUNK), dim3(256), 0, stream>>>(x, w1, w2, y);
}